// Round 9
// baseline (97.098 us; speedup 1.0000x reference)
//
#include <hip/hip_runtime.h>
#include <hip/hip_bf16.h>

#define ALPHA 0.2f

constexpr int B = 8, N = 2048, F = 64;

typedef __attribute__((ext_vector_type(8))) short bf16x8;
typedef __attribute__((ext_vector_type(4))) float f32x4;

__device__ __forceinline__ float lrelu(float x) { return fmaxf(x, ALPHA * x); }

// ---------------- K1: h = inp@W ; f1 ; f2 ; hT (bf16, transposed, PLAIN layout)
//                   + per-batch f2max via signed float atomic-max trick
__global__ __launch_bounds__(256) void k1_project(
    const float* __restrict__ inp, const float* __restrict__ W,
    const float* __restrict__ a,
    __hip_bfloat16* __restrict__ hT, float* __restrict__ f1, float* __restrict__ f2,
    float* __restrict__ f2m)
{
  __shared__ float Wl[64][64];
  __shared__ float inpl[32][64];
  __shared__ float red[32][8][2];
  __shared__ __hip_bfloat16 hl[32][64];
  __shared__ float al[128];

  const int tid = threadIdx.x;
  const int g0 = blockIdx.x * 32;
  const int b = g0 / N, i0 = g0 % N;

  #pragma unroll
  for (int m = 0; m < 4; ++m) {
    int off = m * 1024 + tid * 4;
    *(float4*)((float*)Wl + off) = *(const float4*)(W + off);
  }
  #pragma unroll
  for (int m = 0; m < 2; ++m) {
    int off = m * 1024 + tid * 4;
    *(float4*)((float*)inpl + off) = *(const float4*)(inp + (size_t)g0 * F + off);
  }
  if (tid < 128) al[tid] = a[tid];
  __syncthreads();

  const int r = tid >> 3, c0 = (tid & 7) * 8;
  float acc[8];
  #pragma unroll
  for (int c = 0; c < 8; ++c) acc[c] = 0.f;
  for (int k = 0; k < 64; ++k) {
    float v = inpl[r][k];
    #pragma unroll
    for (int c = 0; c < 8; ++c) acc[c] += v * Wl[k][c0 + c];
  }
  float p1 = 0.f, p2 = 0.f;
  unsigned short hb[8] __attribute__((aligned(16)));
  #pragma unroll
  for (int c = 0; c < 8; ++c) {
    p1 += acc[c] * al[c0 + c];
    p2 += acc[c] * al[64 + c0 + c];
    __hip_bfloat16 hv = __float2bfloat16(acc[c]);
    hb[c] = *(unsigned short*)&hv;
  }
  red[r][tid & 7][0] = p1;
  red[r][tid & 7][1] = p2;
  *(uint4*)&hl[r][c0] = *(uint4*)hb;
  __syncthreads();

  if (tid < 32) {
    float s1 = 0.f, s2 = 0.f;
    #pragma unroll
    for (int m = 0; m < 8; ++m) { s1 += red[tid][m][0]; s2 += red[tid][m][1]; }
    f1[g0 + tid] = s1;
    f2[g0 + tid] = s2;
    // block max of s2 -> one atomic per block (init pattern 0xFFFFFFFF works
    // for both paths: as int = -1 < any positive-float bits; as unsigned = max)
    float mx = s2;
    #pragma unroll
    for (int w = 16; w >= 1; w >>= 1) mx = fmaxf(mx, __shfl_xor(mx, w, 32));
    if (tid == 0) {
      if (mx >= 0.f) atomicMax((int*)&f2m[b], __float_as_int(mx));
      else atomicMin((unsigned int*)&f2m[b], (unsigned int)__float_as_int(mx));
    }
  }
  // plain transposed store: hT[b][c][j]
  const int c = tid >> 2, r8 = (tid & 3) * 8;
  unsigned short tb[8] __attribute__((aligned(16)));
  #pragma unroll
  for (int m = 0; m < 8; ++m) tb[m] = *(unsigned short*)&hl[r8 + m][c];
  *(uint4*)(hT + ((size_t)b * F + c) * N + i0 + r8) = *(uint4*)tb;
}

// ---------------- K3: barrier-free fused mask+softmax+PV+elu
// Each wave owns 16 output rows x all 64 cols for ONE j-chunk (512 cols);
// P entirely in registers (lane computes exactly its A-frag slots); H read
// as B-frags directly from global (L2-resident). No LDS/barriers in the loop.
// s_nop 2 inside each MFMA asm: the compiler's hazard recognizer cannot see
// MFMA inside inline asm, so the required VALU-write->MFMA-read wait states
// (A-frag is packed by VALU immediately before) must be inserted manually.
__global__ __launch_bounds__(256, 4) void k3_attn(
    const int* __restrict__ adj, const __hip_bfloat16* __restrict__ hT,
    const float* __restrict__ f1, const float* __restrict__ f2,
    const float* __restrict__ f2max, float* __restrict__ out)
{
  __shared__ float f2l[N];            // 8KB (read-only after load)
  __shared__ float redt[4][16][66];   // 16.5KB (+2 pad)
  __shared__ float rs[4][16];
  __shared__ float rcp_s[16];

  const int tid = threadIdx.x, lane = tid & 63, wv = tid >> 6;
  const int bi = blockIdx.x;          // 1024 blocks = 8 batches x 128 row-groups
  const int b = bi >> 7;
  const int i0 = (bi & 127) << 4;     // 16 rows per block
  const int l15 = lane & 15, kg = lane >> 4;

  #pragma unroll
  for (int m = 0; m < 2; ++m) {
    const int idx = tid * 8 + m * 4;
    *(float4*)&f2l[idx] = *(const float4*)(f2 + b * N + idx);
  }
  const float f1r = f1[b * N + i0 + l15];
  const float Mr = lrelu(f1r + f2max[b]);   // >= true masked row max (monotone)
  __syncthreads();

  const int jbase = wv * 512 + kg * 8;      // wave's j-chunk + lane k-slice
  const int* adjp = adj + ((size_t)(b * N + i0 + l15)) * N + jbase;
  const __hip_bfloat16* hp = hT + ((size_t)(b * F + l15)) * N + jbase;

  f32x4 acc0 = {0.f,0.f,0.f,0.f}, acc1 = {0.f,0.f,0.f,0.f};
  f32x4 acc2 = {0.f,0.f,0.f,0.f}, acc3 = {0.f,0.f,0.f,0.f};
  float rowsum = 0.f;

  // prefetch step 0
  int4 a0 = *(const int4*)(adjp);
  int4 a1 = *(const int4*)(adjp + 4);
  uint4 h0 = *(const uint4*)(hp);
  uint4 h1 = *(const uint4*)(hp + 16 * N);
  uint4 h2 = *(const uint4*)(hp + 32 * N);
  uint4 h3 = *(const uint4*)(hp + 48 * N);

  #pragma unroll
  for (int s = 0; s < 16; ++s) {
    int4 na0, na1; uint4 nh0, nh1, nh2, nh3;
    if (s < 15) {                      // prefetch step s+1 (compile-time guard)
      const int off = (s + 1) * 32;
      na0 = *(const int4*)(adjp + off);
      na1 = *(const int4*)(adjp + off + 4);
      nh0 = *(const uint4*)(hp + off);
      nh1 = *(const uint4*)(hp + off + 16 * N);
      nh2 = *(const uint4*)(hp + off + 32 * N);
      nh3 = *(const uint4*)(hp + off + 48 * N);
    }
    const float4 u0 = *(const float4*)&f2l[jbase + s * 32];
    const float4 u1 = *(const float4*)&f2l[jbase + s * 32 + 4];

    unsigned short pb[8] __attribute__((aligned(16)));
    const int* ai0 = (const int*)&a0;
    const int* ai1 = (const int*)&a1;
    const float* fe0 = (const float*)&u0;
    const float* fe1 = (const float*)&u1;
    #pragma unroll
    for (int e = 0; e < 4; ++e) {
      float p = (ai0[e] > 0) ? __expf(lrelu(f1r + fe0[e]) - Mr) : 0.f;
      __hip_bfloat16 pf = __float2bfloat16(p);
      rowsum += __bfloat162float(pf);   // denominator from ROUNDED p
      pb[e] = *(unsigned short*)&pf;
    }
    #pragma unroll
    for (int e = 0; e < 4; ++e) {
      float p = (ai1[e] > 0) ? __expf(lrelu(f1r + fe1[e]) - Mr) : 0.f;
      __hip_bfloat16 pf = __float2bfloat16(p);
      rowsum += __bfloat162float(pf);
      pb[4 + e] = *(unsigned short*)&pf;
    }
    bf16x8 af = *(bf16x8*)pb;
    asm volatile("s_nop 2\n\tv_mfma_f32_16x16x32_bf16 %0, %1, %2, %0" : "+v"(acc0) : "v"(af), "v"(*(bf16x8*)&h0));
    asm volatile("s_nop 2\n\tv_mfma_f32_16x16x32_bf16 %0, %1, %2, %0" : "+v"(acc1) : "v"(af), "v"(*(bf16x8*)&h1));
    asm volatile("s_nop 2\n\tv_mfma_f32_16x16x32_bf16 %0, %1, %2, %0" : "+v"(acc2) : "v"(af), "v"(*(bf16x8*)&h2));
    asm volatile("s_nop 2\n\tv_mfma_f32_16x16x32_bf16 %0, %1, %2, %0" : "+v"(acc3) : "v"(af), "v"(*(bf16x8*)&h3));
    if (s < 15) { a0 = na0; a1 = na1; h0 = nh0; h1 = nh1; h2 = nh2; h3 = nh3; }
  }

  // per-row denominator: sum over this wave's 4 k-groups...
  rowsum += __shfl_xor(rowsum, 16);
  rowsum += __shfl_xor(rowsum, 32);
  if (lane < 16) rs[wv][lane] = rowsum;
  // park partial O tiles (C/D: col=l15, row=kg*4+z)
  #pragma unroll
  for (int z = 0; z < 4; ++z) {
    redt[wv][kg * 4 + z][ 0 + l15] = acc0[z];
    redt[wv][kg * 4 + z][16 + l15] = acc1[z];
    redt[wv][kg * 4 + z][32 + l15] = acc2[z];
    redt[wv][kg * 4 + z][48 + l15] = acc3[z];
  }
  __syncthreads();
  if (tid < 16) {
    float s = rs[0][tid] + rs[1][tid] + rs[2][tid] + rs[3][tid];
    rcp_s[tid] = 1.0f / fmaxf(s, 1e-30f);
  }
  __syncthreads();
  // ...then sum the 4 wave-partials, normalize, elu, store
  const int c = tid & 63, rq = tid >> 6;
  #pragma unroll
  for (int z = 0; z < 4; ++z) {
    const int row = z * 4 + rq;
    float v = (redt[0][row][c] + redt[1][row][c] + redt[2][row][c] +
               redt[3][row][c]) * rcp_s[row];
    v = v > 0.f ? v : expm1f(v);
    out[((size_t)(b * N + i0 + row)) * F + c] = v;
  }
}

extern "C" void kernel_launch(void* const* d_in, const int* in_sizes, int n_in,
                              void* d_out, int out_size, void* d_ws, size_t ws_size,
                              hipStream_t stream) {
  const float* inp = (const float*)d_in[0];
  const int*   adj = (const int*)d_in[1];
  const float* W   = (const float*)d_in[2];
  const float* a   = (const float*)d_in[3];
  float* out = (float*)d_out;

  char* ws = (char*)d_ws;
  __hip_bfloat16* hT = (__hip_bfloat16*)ws;
  float* f1  = (float*)(ws + (size_t)B * F * N * sizeof(__hip_bfloat16));
  float* f2  = f1 + (size_t)B * N;
  float* f2m = f2 + (size_t)B * N;

  hipMemsetAsync(f2m, 0xFF, B * sizeof(float), stream);  // -inf-equivalent init
  hipLaunchKernelGGL(k1_project, dim3(B * N / 32), dim3(256), 0, stream,
                     inp, W, a, hT, f1, f2, f2m);
  hipLaunchKernelGGL(k3_attn, dim3(B * N / 16), dim3(256), 0, stream,
                     adj, hT, f1, f2, f2m, out);
}